// Round 1
// baseline (240.662 us; speedup 1.0000x reference)
//
#include <hip/hip_runtime.h>
#include <hip/hip_bf16.h>

typedef unsigned long long u64;

#define NB 16
#define HW 512
#define PIX_PER_B (HW * HW)            // 262144
#define NPIX (NB * PIX_PER_B)          // 4194304
#define WORDS_PER_B (PIX_PER_B / 64)   // 4096 (8 u64 words per row)
#define SROW 9                         // LDS row stride in u64 (8 + 1 pad -> 2-way bank alias only)

#define K1_BLOCKS 512
#define WS_PART_OFF 1024
#define WS_MASK_OFF 32768
#define WS_NEED_MASKS (WS_MASK_OFF + (size_t)2 * NB * WORDS_PER_B * 8)

// ---------------- bit-sliced Zhang-Suen helpers ----------------

__device__ __forceinline__ void fa3(u64 a, u64 b, u64 c, u64& s, u64& cy) {
  u64 x = a ^ b;
  s = x ^ c;
  cy = (a & b) | (c & x);
}

// One thinning decision for 64 pixels (one word), given the 3x3 word neighborhood.
// Bit j of a word = pixel at column (word*64 + j). East (col+1) => >>1 with carry
// from the next word's bit0; West (col-1) => <<1 with carry from prev word's bit63.
__device__ __forceinline__ u64 thin_word(u64 nm, u64 nl, u64 nr,
                                         u64 cm, u64 cl, u64 cr,
                                         u64 sm, u64 sl, u64 sr, int sub) {
  u64 p2 = nm;                          // N
  u64 p3 = (nm >> 1) | (nr << 63);      // NE
  u64 p4 = (cm >> 1) | (cr << 63);      // E
  u64 p5 = (sm >> 1) | (sr << 63);      // SE
  u64 p6 = sm;                          // S
  u64 p7 = (sm << 1) | (sl >> 63);      // SW
  u64 p8 = (cm << 1) | (cl >> 63);      // W
  u64 p9 = (nm << 1) | (nl >> 63);      // NW

  // B = sum of 8 neighbor bits, bit-sliced. B = ss + 2*(sc+cs) + 4*cc
  u64 u1, v1, u2, v2, ss, sc, cs, cc;
  fa3(p2, p3, p4, u1, v1);
  fa3(p5, p6, p7, u2, v2);
  u64 u3 = p8 ^ p9, v3 = p8 & p9;
  fa3(u1, u2, u3, ss, sc);
  fa3(v1, v2, v3, cs, cc);
  // 2 <= B <= 6:  B>=2 <=> (sc|cs|cc);  B>=7 <=> b3 | (b2&b1&b0)
  u64 w  = sc & cs;
  u64 b1 = sc ^ cs;
  u64 b2 = cc ^ w;
  u64 b3 = cc & w;
  u64 cond1 = (sc | cs | cc) & ~(b3 | (b2 & b1 & ss));

  // A = number of 0->1 transitions in circular p2..p9; need A == 1
  u64 t0 = ~p2 & p3, t1 = ~p3 & p4, t2 = ~p4 & p5, t3 = ~p5 & p6;
  u64 t4 = ~p6 & p7, t5 = ~p7 & p8, t6 = ~p8 & p9, t7 = ~p9 & p2;
  u64 as1, ac1, as2, ac2, Ass, Asc, Acs, Acc;
  fa3(t0, t1, t2, as1, ac1);
  fa3(t3, t4, t5, as2, ac2);
  u64 as3 = t6 ^ t7, ac3 = t6 & t7;
  fa3(as1, as2, as3, Ass, Asc);
  fa3(ac1, ac2, ac3, Acs, Acc);
  u64 cond2 = Ass & ~(Asc | Acs | Acc);  // A==1 <=> bit0 set, all higher weights 0

  u64 cond3, cond4;
  if (sub == 0) { cond3 = ~(p2 & p4 & p6); cond4 = ~(p4 & p6 & p8); }
  else          { cond3 = ~(p2 & p4 & p8); cond4 = ~(p2 & p6 & p8); }

  u64 rem = cm & cond1 & cond2 & cond3 & cond4;
  return cm & ~rem;
}

// ---------------- kernel 1: softmax + dice/focal reductions + binarization masks ----------------

__global__ __launch_bounds__(256) void loss_reduce_kernel(
    const float* __restrict__ logits, const int* __restrict__ tr,
    unsigned char* __restrict__ ws, int writeMasks) {
  int tid = threadIdx.x;
  double a0 = 0, a1 = 0, s0 = 0, s1 = 0, cnt = 0, fo = 0;
  u64* predM = (u64*)(ws + WS_MASK_OFF);
  u64* trueM = predM + (size_t)NB * WORDS_PER_B;

  const int iters = NPIX / (K1_BLOCKS * 256);  // 32
  for (int it = 0; it < iters; ++it) {
    int g = (it * K1_BLOCKS + (int)blockIdx.x) * 256 + tid;
    int b = g >> 18;
    int r = g & (PIX_PER_B - 1);
    const float* lp = logits + (size_t)b * 2 * PIX_PER_B + r;
    float l0 = lp[0], l1 = lp[PIX_PER_B];
    int t = tr[g];
    float m = fmaxf(l0, l1);
    float e0 = expf(l0 - m), e1 = expf(l1 - m);
    float s = e0 + e1;
    float p0 = e0 / s, p1 = e1 / s;
    if (t) a1 += (double)p1; else a0 += (double)p0;
    s0 += (double)p0;
    s1 += (double)p1;
    cnt += (double)t;
    float lse = m + logf(s);
    float ce = lse - (t ? l1 : l0);     // -log p_true
    float pt = t ? p1 : p0;             // exp(-ce)
    float om = 1.0f - pt;
    fo += (double)(0.25f * om * om * ce);
    if (writeMasks) {
      u64 pm = __ballot(p1 > 0.5f);
      u64 tm = __ballot(t > 0);
      if ((tid & 63) == 0) { predM[g >> 6] = pm; trueM[g >> 6] = tm; }
    }
  }

  __shared__ double red[4][6];
  double v[6] = {a0, a1, s0, s1, cnt, fo};
  int lane = tid & 63, wv = tid >> 6;
#pragma unroll
  for (int j = 0; j < 6; j++) {
    double x = v[j];
    for (int o = 32; o; o >>= 1) x += __shfl_down(x, o, 64);
    if (lane == 0) red[wv][j] = x;
  }
  __syncthreads();
  if (tid < 6) {
    double* part = (double*)(ws + WS_PART_OFF) + (size_t)blockIdx.x * 6;
    part[tid] = red[0][tid] + red[1][tid] + red[2][tid] + red[3][tid];
  }
}

// ---------------- kernel 2: skeletonize both images per batch, accumulate clDice counters ----------------

__global__ __launch_bounds__(1024) void skel_kernel(
    const float* __restrict__ logits, const int* __restrict__ tr,
    unsigned char* __restrict__ ws, int useMasks) {
  __shared__ u64 S[HW * SROW];   // one bit-packed 512x512 image, padded rows (36 KB)
  __shared__ int flag;

  int tid  = threadIdx.x;
  int b    = blockIdx.x;
  int wcol = tid & 7;            // word column 0..7
  int r0   = (tid >> 3) * 4;     // 4-row strip
  int lane = tid & 63;

  u64* clInter = (u64*)(ws + 64);
  u64* clSp    = (u64*)(ws + 192);
  u64* clSt    = (u64*)(ws + 320);
  const u64* predM = (const u64*)(ws + WS_MASK_OFF) + (size_t)b * WORDS_PER_B;
  const u64* trueM = (const u64*)(ws + WS_MASK_OFF) + (size_t)(NB + b) * WORDS_PER_B;

  auto buildFromMask = [&](const u64* M) {
#pragma unroll
    for (int i = 0; i < 4; i++)
      S[(r0 + i) * SROW + wcol] = M[(r0 + i) * 8 + wcol];
    __syncthreads();
  };
  auto buildPredCompute = [&]() {
    const float* lp0 = logits + (size_t)b * 2 * PIX_PER_B;
    const float* lp1 = lp0 + PIX_PER_B;
    for (int k = 0; k < PIX_PER_B / 1024; k++) {
      int p = k * 1024 + tid;
      float l0 = lp0[p], l1 = lp1[p];
      float m = fmaxf(l0, l1);
      float e0 = expf(l0 - m), e1 = expf(l1 - m);
      float p1v = e1 / (e0 + e1);
      u64 msk = __ballot(p1v > 0.5f);
      if (lane == 0) { int wi = p >> 6; S[(wi >> 3) * SROW + (wi & 7)] = msk; }
    }
    __syncthreads();
  };
  auto buildTrueCompute = [&]() {
    const int* tp = tr + (size_t)b * PIX_PER_B;
    for (int k = 0; k < PIX_PER_B / 1024; k++) {
      int p = k * 1024 + tid;
      u64 msk = __ballot(tp[p] > 0);
      if (lane == 0) { int wi = p >> 6; S[(wi >> 3) * SROW + (wi & 7)] = msk; }
    }
    __syncthreads();
  };

  auto loadRow = [&](int r, u64& m, u64& l, u64& rr) {
    if (r < 0 || r >= HW) { m = 0; l = 0; rr = 0; return; }
    const u64* row = &S[r * SROW];
    m  = row[wcol];
    l  = wcol ? row[wcol - 1] : 0ULL;
    rr = (wcol < 7) ? row[wcol + 1] : 0ULL;
  };

  auto subIter = [&](int sub) {
    u64 am, al, ar, bm, bl, br, cmv, clv, crv;
    u64 nw[4], oldc[4];
    loadRow(r0 - 1, am, al, ar);
    loadRow(r0,     bm, bl, br);
#pragma unroll
    for (int i = 0; i < 4; i++) {
      loadRow(r0 + 1 + i, cmv, clv, crv);
      oldc[i] = bm;
      nw[i] = thin_word(am, al, ar, bm, bl, br, cmv, clv, crv, sub);
      am = bm; al = bl; ar = br;
      bm = cmv; bl = clv; br = crv;
    }
    __syncthreads();                 // all reads of old state done
    bool ch = false;
#pragma unroll
    for (int i = 0; i < 4; i++) {
      S[(r0 + i) * SROW + wcol] = nw[i];
      ch |= (nw[i] != oldc[i]);
    }
    if (ch) flag = 1;                // benign same-value race
    __syncthreads();                 // writes + flag visible
  };

  auto thinConverge = [&]() {
    for (int it = 0; it < 2000; ++it) {
      if (tid == 0) flag = 0;
      __syncthreads();
      subIter(0);
      subIter(1);
      int f = flag;
      __syncthreads();               // all reads of flag before next reset
      if (!f) break;                 // uniform
    }
  };

  // ---- pred skeleton ----
  if (useMasks) buildFromMask(predM); else buildPredCompute();
  thinConverge();
  u64 pr[4];
  u64 spL = 0;
#pragma unroll
  for (int i = 0; i < 4; i++) {
    pr[i] = S[(r0 + i) * SROW + wcol];
    spL += (u64)__popcll(pr[i]);
  }
  __syncthreads();                   // everyone saved before S is reused

  // ---- true skeleton (reuse LDS) ----
  if (useMasks) buildFromMask(trueM); else buildTrueCompute();
  thinConverge();
  u64 stL = 0, inL = 0;
#pragma unroll
  for (int i = 0; i < 4; i++) {
    u64 tw = S[(r0 + i) * SROW + wcol];
    stL += (u64)__popcll(tw);
    inL += (u64)__popcll(tw & pr[i]);
  }

  for (int o = 32; o; o >>= 1) {
    spL += __shfl_down(spL, o, 64);
    stL += __shfl_down(stL, o, 64);
    inL += __shfl_down(inL, o, 64);
  }
  if (lane == 0) {
    atomicAdd(clSp + b, spL);
    atomicAdd(clSt + b, stL);
    atomicAdd(clInter + b, inL);
  }
}

// ---------------- kernel 3: finalize scalar loss ----------------

__global__ void finalize_kernel(unsigned char* __restrict__ ws, float* __restrict__ out) {
  const double* part = (const double*)(ws + WS_PART_OFF);
  double a0 = 0, a1 = 0, s0 = 0, s1 = 0, cnt = 0, fo = 0;
  for (int i = 0; i < K1_BLOCKS; i++) {
    const double* p = part + (size_t)i * 6;
    a0 += p[0]; a1 += p[1]; s0 += p[2]; s1 += p[3]; cnt += p[4]; fo += p[5];
  }
  const double N = (double)NPIX;
  double cnt0 = N - cnt;
  double card0 = s0 + cnt0, card1 = s1 + cnt;
  double dice = 0.5 * ((2.0 * a0 + 1e-6) / (card0 + 1e-6) +
                       (2.0 * a1 + 1e-6) / (card1 + 1e-6));
  double diceL = 1.0 - dice;
  double focalL = fo / N;

  const u64* clInter = (const u64*)(ws + 64);
  const u64* clSp    = (const u64*)(ws + 192);
  const u64* clSt    = (const u64*)(ws + 320);
  double cs = 0;
  for (int b = 0; b < NB; b++) {
    double inter = (double)clInter[b];
    double den = (double)(clSp[b] + clSt[b]);
    cs += (2.0 * inter + 1e-6) / (den + 1e-6);
  }
  double clL = 1.0 - cs / (double)NB;

  out[0] = (float)(0.7 * clL + 0.1 * diceL + 0.2 * focalL);
}

// ---------------- launch ----------------

extern "C" void kernel_launch(void* const* d_in, const int* in_sizes, int n_in,
                              void* d_out, int out_size, void* d_ws, size_t ws_size,
                              hipStream_t stream) {
  const float* logits = (const float*)d_in[0];
  const int* tr = (const int*)d_in[1];
  float* out = (float*)d_out;
  unsigned char* ws = (unsigned char*)d_ws;

  int useMasks = (ws_size >= WS_NEED_MASKS) ? 1 : 0;

  // zero the clDice counters (offsets 64..448); partials/masks fully overwritten
  hipMemsetAsync(d_ws, 0, 512, stream);

  hipLaunchKernelGGL(loss_reduce_kernel, dim3(K1_BLOCKS), dim3(256), 0, stream,
                     logits, tr, ws, useMasks);
  hipLaunchKernelGGL(skel_kernel, dim3(NB), dim3(1024), 0, stream,
                     logits, tr, ws, useMasks);
  hipLaunchKernelGGL(finalize_kernel, dim3(1), dim3(1), 0, stream, ws, out);
}

// Round 2
// 144.613 us; speedup vs baseline: 1.6642x; 1.6642x over previous
//
#include <hip/hip_runtime.h>
#include <hip/hip_bf16.h>

typedef unsigned long long u64;

#define NB 16
#define HW 512
#define PIX_PER_B (HW * HW)            // 262144
#define NPIX (NB * PIX_PER_B)          // 4194304
#define WORDS_PER_B (PIX_PER_B / 64)   // 4096 (8 u64 words per row)
#define SROW 9                         // LDS row stride in u64 (8 + 1 pad)

#define K1_BLOCKS 512
#define WS_PART_OFF 1024
#define WS_MASK_OFF 32768
// 32 image regions (16 pred + 16 true), 32 KB each; masks in, skeletons out
#define WS_NEED_MASKS (WS_MASK_OFF + (size_t)2 * NB * WORDS_PER_B * 8)

// ---------------- bit-sliced Zhang-Suen helpers ----------------

__device__ __forceinline__ void fa3(u64 a, u64 b, u64 c, u64& s, u64& cy) {
  u64 x = a ^ b;
  s = x ^ c;
  cy = (a & b) | (c & x);
}

__device__ __forceinline__ u64 thin_word(u64 nm, u64 nl, u64 nr,
                                         u64 cm, u64 cl, u64 cr,
                                         u64 sm, u64 sl, u64 sr, int sub) {
  u64 p2 = nm;                          // N
  u64 p3 = (nm >> 1) | (nr << 63);      // NE
  u64 p4 = (cm >> 1) | (cr << 63);      // E
  u64 p5 = (sm >> 1) | (sr << 63);      // SE
  u64 p6 = sm;                          // S
  u64 p7 = (sm << 1) | (sl >> 63);      // SW
  u64 p8 = (cm << 1) | (cl >> 63);      // W
  u64 p9 = (nm << 1) | (nl >> 63);      // NW

  u64 u1, v1, u2, v2, ss, sc, cs, cc;
  fa3(p2, p3, p4, u1, v1);
  fa3(p5, p6, p7, u2, v2);
  u64 u3 = p8 ^ p9, v3 = p8 & p9;
  fa3(u1, u2, u3, ss, sc);
  fa3(v1, v2, v3, cs, cc);
  u64 w  = sc & cs;
  u64 b1 = sc ^ cs;
  u64 b2 = cc ^ w;
  u64 b3 = cc & w;
  u64 cond1 = (sc | cs | cc) & ~(b3 | (b2 & b1 & ss));  // 2 <= B <= 6

  u64 t0 = ~p2 & p3, t1 = ~p3 & p4, t2 = ~p4 & p5, t3 = ~p5 & p6;
  u64 t4 = ~p6 & p7, t5 = ~p7 & p8, t6 = ~p8 & p9, t7 = ~p9 & p2;
  u64 as1, ac1, as2, ac2, Ass, Asc, Acs, Acc;
  fa3(t0, t1, t2, as1, ac1);
  fa3(t3, t4, t5, as2, ac2);
  u64 as3 = t6 ^ t7, ac3 = t6 & t7;
  fa3(as1, as2, as3, Ass, Asc);
  fa3(ac1, ac2, ac3, Acs, Acc);
  u64 cond2 = Ass & ~(Asc | Acs | Acc);  // A == 1

  u64 cond3, cond4;
  if (sub == 0) { cond3 = ~(p2 & p4 & p6); cond4 = ~(p4 & p6 & p8); }
  else          { cond3 = ~(p2 & p4 & p8); cond4 = ~(p2 & p6 & p8); }

  u64 rem = cm & cond1 & cond2 & cond3 & cond4;
  return cm & ~rem;
}

// ---------------- kernel 1: softmax + dice/focal reductions + binarization masks ----------------

__global__ __launch_bounds__(256) void loss_reduce_kernel(
    const float* __restrict__ logits, const int* __restrict__ tr,
    unsigned char* __restrict__ ws, int writeMasks) {
  int tid = threadIdx.x;
  double a0 = 0, a1 = 0, s0 = 0, s1 = 0, cnt = 0, fo = 0;
  u64* predM = (u64*)(ws + WS_MASK_OFF);
  u64* trueM = predM + (size_t)NB * WORDS_PER_B;

  const int iters = NPIX / (K1_BLOCKS * 256);  // 32
  for (int it = 0; it < iters; ++it) {
    int g = (it * K1_BLOCKS + (int)blockIdx.x) * 256 + tid;
    int b = g >> 18;
    int r = g & (PIX_PER_B - 1);
    const float* lp = logits + (size_t)b * 2 * PIX_PER_B + r;
    float l0 = lp[0], l1 = lp[PIX_PER_B];
    int t = tr[g];
    float m = fmaxf(l0, l1);
    float e0 = expf(l0 - m), e1 = expf(l1 - m);
    float s = e0 + e1;
    float p0 = e0 / s, p1 = e1 / s;
    if (t) a1 += (double)p1; else a0 += (double)p0;
    s0 += (double)p0;
    s1 += (double)p1;
    cnt += (double)t;
    float lse = m + logf(s);
    float ce = lse - (t ? l1 : l0);
    float pt = t ? p1 : p0;
    float om = 1.0f - pt;
    fo += (double)(0.25f * om * om * ce);
    if (writeMasks) {
      u64 pm = __ballot(p1 > 0.5f);
      u64 tm = __ballot(t > 0);
      if ((tid & 63) == 0) { predM[g >> 6] = pm; trueM[g >> 6] = tm; }
    }
  }

  __shared__ double red[4][6];
  double v[6] = {a0, a1, s0, s1, cnt, fo};
  int lane = tid & 63, wv = tid >> 6;
#pragma unroll
  for (int j = 0; j < 6; j++) {
    double x = v[j];
    for (int o = 32; o; o >>= 1) x += __shfl_down(x, o, 64);
    if (lane == 0) red[wv][j] = x;
  }
  __syncthreads();
  if (tid < 6) {
    double* part = (double*)(ws + WS_PART_OFF) + (size_t)blockIdx.x * 6;
    part[tid] = red[0][tid] + red[1][tid] + red[2][tid] + red[3][tid];
  }
}

// ---------------- kernel 2 (main path): one block per image (32 blocks) ----------------
// Block b<16: pred image b. Block b>=16: true image b-16. Reads bit-mask from its ws
// region, thins to convergence in LDS with dirty-strip wave-skipping, writes the
// skeleton back to the same region, atomicAdds its popcount (sp or st).

__global__ __launch_bounds__(1024) void skel_split_kernel(unsigned char* __restrict__ ws) {
  __shared__ u64 S[HW * SROW];                  // 36 KB
  __shared__ unsigned char dirty[2][130];       // +1-offset strip dirty, 2 sub-iter history
  __shared__ int flag;

  int tid  = threadIdx.x;
  int b    = blockIdx.x;                        // 0..31
  int img  = b & 15;
  int wcol = tid & 7;
  int s    = tid >> 3;                          // strip 0..127 (4 rows each)
  int r0   = s * 4;
  int lane = tid & 63;

  u64* region = (u64*)(ws + WS_MASK_OFF) + (size_t)b * WORDS_PER_B;
  u64* clSp = (u64*)(ws + 192);
  u64* clSt = (u64*)(ws + 320);

#pragma unroll
  for (int i = 0; i < 4; i++)
    S[(r0 + i) * SROW + wcol] = region[(r0 + i) * 8 + wcol];
  if (tid < 130) {
    unsigned char init = (tid >= 1 && tid <= 128) ? 1 : 0;
    dirty[0][tid] = init;
    dirty[1][tid] = init;
  }
  if (tid == 0) flag = 0;
  __syncthreads();

  auto loadRow = [&](int r, u64& m, u64& l, u64& rr) {
    if (r < 0 || r >= HW) { m = 0; l = 0; rr = 0; return; }
    const u64* row = &S[r * SROW];
    m  = row[wcol];
    l  = wcol ? row[wcol - 1] : 0ULL;
    rr = (wcol < 7) ? row[wcol + 1] : 0ULL;
  };

  auto subIter = [&](int sub, int db, int pairTag) {
    unsigned char* dOut = dirty[db ^ 1];
    // gate: strip can change only if itself/neighbors changed in last TWO sub-iters
    // (parity: this sub's map was last applied two sub-iters ago)
    bool laneActive = (dirty[0][s] | dirty[0][s + 1] | dirty[0][s + 2] |
                       dirty[1][s] | dirty[1][s + 1] | dirty[1][s + 2]) != 0;
    u64 wmask = __ballot(laneActive);           // whole-wave skip (32-row band)
    bool stripCh = false;
    u64 nw[4];
    bool doit = (wmask != 0);
    if (doit) {
      u64 am, al, ar, bm, bl, br, cmv, clv, crv, oldc[4];
      loadRow(r0 - 1, am, al, ar);
      loadRow(r0,     bm, bl, br);
#pragma unroll
      for (int i = 0; i < 4; i++) {
        loadRow(r0 + 1 + i, cmv, clv, crv);
        oldc[i] = bm;
        nw[i] = thin_word(am, al, ar, bm, bl, br, cmv, clv, crv, sub);
        am = bm; al = bl; ar = br;
        bm = cmv; bl = clv; br = crv;
      }
      bool ch = false;
#pragma unroll
      for (int i = 0; i < 4; i++) ch |= (nw[i] != oldc[i]);
      u64 bal = __ballot(ch);
      stripCh = ((bal >> (lane & 56)) & 0xFFULL) != 0;
    }
    __syncthreads();                            // all reads of old state done
    if (doit) {
#pragma unroll
      for (int i = 0; i < 4; i++) S[(r0 + i) * SROW + wcol] = nw[i];
    }
    if ((tid & 7) == 0) {
      dOut[s + 1] = stripCh ? 1 : 0;
      if (stripCh) flag = pairTag;              // benign same-value race
    }
    __syncthreads();                            // writes + dirty + flag visible
  };

  for (int pair = 1; pair <= 2000; ++pair) {
    subIter(0, 0, pair);
    subIter(1, 1, pair);
    if (flag != pair) break;                    // uniform; all reads precede next write phase
  }

  u64 cnt = 0;
#pragma unroll
  for (int i = 0; i < 4; i++) {
    u64 w = S[(r0 + i) * SROW + wcol];
    region[(r0 + i) * 8 + wcol] = w;            // skeleton out (overwrites mask)
    cnt += (u64)__popcll(w);
  }
  for (int o = 32; o; o >>= 1) cnt += __shfl_down(cnt, o, 64);
  if (lane == 0) atomicAdd((b < NB ? clSp : clSt) + img, cnt);
}

// ---------------- kernel 2b (fallback, ws too small): combined per-batch ----------------

__global__ __launch_bounds__(1024) void skel_combined_kernel(
    const float* __restrict__ logits, const int* __restrict__ tr,
    unsigned char* __restrict__ ws) {
  __shared__ u64 S[HW * SROW];
  __shared__ int flag;

  int tid  = threadIdx.x;
  int b    = blockIdx.x;
  int wcol = tid & 7;
  int r0   = (tid >> 3) * 4;
  int lane = tid & 63;

  u64* clInter = (u64*)(ws + 64);
  u64* clSp    = (u64*)(ws + 192);
  u64* clSt    = (u64*)(ws + 320);

  auto buildPredCompute = [&]() {
    const float* lp0 = logits + (size_t)b * 2 * PIX_PER_B;
    const float* lp1 = lp0 + PIX_PER_B;
    for (int k = 0; k < PIX_PER_B / 1024; k++) {
      int p = k * 1024 + tid;
      float l0 = lp0[p], l1 = lp1[p];
      float m = fmaxf(l0, l1);
      float e0 = expf(l0 - m), e1 = expf(l1 - m);
      float p1v = e1 / (e0 + e1);
      u64 msk = __ballot(p1v > 0.5f);
      if (lane == 0) { int wi = p >> 6; S[(wi >> 3) * SROW + (wi & 7)] = msk; }
    }
    __syncthreads();
  };
  auto buildTrueCompute = [&]() {
    const int* tp = tr + (size_t)b * PIX_PER_B;
    for (int k = 0; k < PIX_PER_B / 1024; k++) {
      int p = k * 1024 + tid;
      u64 msk = __ballot(tp[p] > 0);
      if (lane == 0) { int wi = p >> 6; S[(wi >> 3) * SROW + (wi & 7)] = msk; }
    }
    __syncthreads();
  };

  auto loadRow = [&](int r, u64& m, u64& l, u64& rr) {
    if (r < 0 || r >= HW) { m = 0; l = 0; rr = 0; return; }
    const u64* row = &S[r * SROW];
    m  = row[wcol];
    l  = wcol ? row[wcol - 1] : 0ULL;
    rr = (wcol < 7) ? row[wcol + 1] : 0ULL;
  };

  auto subIter = [&](int sub) {
    u64 am, al, ar, bm, bl, br, cmv, clv, crv;
    u64 nw[4], oldc[4];
    loadRow(r0 - 1, am, al, ar);
    loadRow(r0,     bm, bl, br);
#pragma unroll
    for (int i = 0; i < 4; i++) {
      loadRow(r0 + 1 + i, cmv, clv, crv);
      oldc[i] = bm;
      nw[i] = thin_word(am, al, ar, bm, bl, br, cmv, clv, crv, sub);
      am = bm; al = bl; ar = br;
      bm = cmv; bl = clv; br = crv;
    }
    __syncthreads();
    bool ch = false;
#pragma unroll
    for (int i = 0; i < 4; i++) {
      S[(r0 + i) * SROW + wcol] = nw[i];
      ch |= (nw[i] != oldc[i]);
    }
    if (ch) flag = 1;
    __syncthreads();
  };

  auto thinConverge = [&]() {
    for (int it = 0; it < 2000; ++it) {
      if (tid == 0) flag = 0;
      __syncthreads();
      subIter(0);
      subIter(1);
      int f = flag;
      __syncthreads();
      if (!f) break;
    }
  };

  buildPredCompute();
  thinConverge();
  u64 pr[4];
  u64 spL = 0;
#pragma unroll
  for (int i = 0; i < 4; i++) {
    pr[i] = S[(r0 + i) * SROW + wcol];
    spL += (u64)__popcll(pr[i]);
  }
  __syncthreads();

  buildTrueCompute();
  thinConverge();
  u64 stL = 0, inL = 0;
#pragma unroll
  for (int i = 0; i < 4; i++) {
    u64 tw = S[(r0 + i) * SROW + wcol];
    stL += (u64)__popcll(tw);
    inL += (u64)__popcll(tw & pr[i]);
  }

  for (int o = 32; o; o >>= 1) {
    spL += __shfl_down(spL, o, 64);
    stL += __shfl_down(stL, o, 64);
    inL += __shfl_down(inL, o, 64);
  }
  if (lane == 0) {
    atomicAdd(clSp + b, spL);
    atomicAdd(clSt + b, stL);
    atomicAdd(clInter + b, inL);
  }
}

// ---------------- kernel 3 (main path): intersection popcount ----------------

__global__ __launch_bounds__(256) void inter_kernel(unsigned char* __restrict__ ws) {
  int i = blockIdx.x;
  int tid = threadIdx.x;
  const u64* p = (const u64*)(ws + WS_MASK_OFF) + (size_t)i * WORDS_PER_B;
  const u64* t = p + (size_t)NB * WORDS_PER_B;
  u64 acc = 0;
  for (int w = tid; w < WORDS_PER_B; w += 256) acc += (u64)__popcll(p[w] & t[w]);
  for (int o = 32; o; o >>= 1) acc += __shfl_down(acc, o, 64);
  __shared__ u64 r[4];
  if ((tid & 63) == 0) r[tid >> 6] = acc;
  __syncthreads();
  if (tid == 0) {
    u64* clInter = (u64*)(ws + 64);
    clInter[i] = r[0] + r[1] + r[2] + r[3];
  }
}

// ---------------- kernel 4: finalize (parallel partial reduction) ----------------

__global__ __launch_bounds__(512) void finalize_kernel(unsigned char* __restrict__ ws,
                                                       float* __restrict__ out) {
  int tid = threadIdx.x;
  const double* part = (const double*)(ws + WS_PART_OFF);
  double v[6];
#pragma unroll
  for (int j = 0; j < 6; j++) v[j] = part[(size_t)tid * 6 + j];

  __shared__ double red[8][6];
  int lane = tid & 63, wv = tid >> 6;
#pragma unroll
  for (int j = 0; j < 6; j++) {
    double x = v[j];
    for (int o = 32; o; o >>= 1) x += __shfl_down(x, o, 64);
    if (lane == 0) red[wv][j] = x;
  }
  __syncthreads();
  if (tid == 0) {
    double t[6] = {0, 0, 0, 0, 0, 0};
    for (int w = 0; w < 8; w++)
      for (int j = 0; j < 6; j++) t[j] += red[w][j];
    double a0 = t[0], a1 = t[1], s0 = t[2], s1 = t[3], cnt = t[4], fo = t[5];

    const double N = (double)NPIX;
    double cnt0 = N - cnt;
    double card0 = s0 + cnt0, card1 = s1 + cnt;
    double dice = 0.5 * ((2.0 * a0 + 1e-6) / (card0 + 1e-6) +
                         (2.0 * a1 + 1e-6) / (card1 + 1e-6));
    double diceL = 1.0 - dice;
    double focalL = fo / N;

    const u64* clInter = (const u64*)(ws + 64);
    const u64* clSp    = (const u64*)(ws + 192);
    const u64* clSt    = (const u64*)(ws + 320);
    double cs = 0;
    for (int b = 0; b < NB; b++) {
      double inter = (double)clInter[b];
      double den = (double)(clSp[b] + clSt[b]);
      cs += (2.0 * inter + 1e-6) / (den + 1e-6);
    }
    double clL = 1.0 - cs / (double)NB;

    out[0] = (float)(0.7 * clL + 0.1 * diceL + 0.2 * focalL);
  }
}

// ---------------- launch ----------------

extern "C" void kernel_launch(void* const* d_in, const int* in_sizes, int n_in,
                              void* d_out, int out_size, void* d_ws, size_t ws_size,
                              hipStream_t stream) {
  const float* logits = (const float*)d_in[0];
  const int* tr = (const int*)d_in[1];
  float* out = (float*)d_out;
  unsigned char* ws = (unsigned char*)d_ws;

  int useMasks = (ws_size >= WS_NEED_MASKS) ? 1 : 0;

  hipMemsetAsync(d_ws, 0, 512, stream);  // zero clDice counters

  hipLaunchKernelGGL(loss_reduce_kernel, dim3(K1_BLOCKS), dim3(256), 0, stream,
                     logits, tr, ws, useMasks);
  if (useMasks) {
    hipLaunchKernelGGL(skel_split_kernel, dim3(2 * NB), dim3(1024), 0, stream, ws);
    hipLaunchKernelGGL(inter_kernel, dim3(NB), dim3(256), 0, stream, ws);
  } else {
    hipLaunchKernelGGL(skel_combined_kernel, dim3(NB), dim3(1024), 0, stream,
                       logits, tr, ws);
  }
  hipLaunchKernelGGL(finalize_kernel, dim3(1), dim3(512), 0, stream, ws, out);
}